// Round 7
// baseline (154.506 us; speedup 1.0000x reference)
//
#include <hip/hip_runtime.h>

#define EMB 512
#define HEADS 8
#define HD 64
#define NSEQ 4096
#define BATCH 2
#define WINDOW 128

typedef unsigned short u16;
typedef __attribute__((ext_vector_type(8))) short bf16x8;
typedef __attribute__((ext_vector_type(4))) float f32x4;

#define XS 4194304u   // x elems (2*4096*512)
#define WS 262144u    // one weight matrix elems
#define BS 512u       // one bias elems

__device__ __forceinline__ float bf2f(u16 u) {
    union { unsigned int i; float f; } x;
    x.i = ((unsigned int)u) << 16;
    return x.f;
}

__device__ __forceinline__ u16 f2bf(float f) {
    union { float f; unsigned int i; } x;
    x.f = f;
    unsigned int i = x.i;
    unsigned int lsb = (i >> 16) & 1u;
    i += 0x7fffu + lsb;   // round-to-nearest-even
    return (u16)(i >> 16);
}

struct raw8 { uint4 lo, hi; };

__device__ __forceinline__ raw8 loadraw8(const void* base, size_t off, int isbf) {
    raw8 r;
    if (isbf) {
        r.lo = *(const uint4*)((const u16*)base + off);
    } else {
        const float* f = (const float*)base + off;
        r.lo = *(const uint4*)f;
        r.hi = *(const uint4*)(f + 4);
    }
    return r;
}

__device__ __forceinline__ uint4 cvt8(const raw8& r, int isbf) {
    if (isbf) return r.lo;
    const float* a = (const float*)&r.lo;
    const float* b = (const float*)&r.hi;
    uint4 o;
    o.x = (unsigned)f2bf(a[0]) | ((unsigned)f2bf(a[1]) << 16);
    o.y = (unsigned)f2bf(a[2]) | ((unsigned)f2bf(a[3]) << 16);
    o.z = (unsigned)f2bf(b[0]) | ((unsigned)f2bf(b[1]) << 16);
    o.w = (unsigned)f2bf(b[2]) | ((unsigned)f2bf(b[3]) << 16);
    return o;
}

__device__ __forceinline__ int probe_bf16(const void* p) {
    const int lane = threadIdx.x & 63;
    u16 w = ((const u16*)p)[lane * 2];
    int e = (w >> 7) & 0xff;
    bool sane = (w == 0) || (e >= 100 && e <= 140);
    unsigned long long m = __ballot(sane);
    return __popcll(m) >= 48;
}

// ---------------------------------------------------------------------------
// Pre-pass: convert x, Wq,Wk,Wv,Wo, bq,bk,bv,bo to bf16 in ws. flags[0] = x
// dtype (also the output dtype). grid: 2561 x 256.
// ---------------------------------------------------------------------------
__global__ __launch_bounds__(256)
void prepass(const void* __restrict__ x,
             const void* __restrict__ Wq, const void* __restrict__ bq,
             const void* __restrict__ Wk, const void* __restrict__ bk,
             const void* __restrict__ Wv, const void* __restrict__ bv,
             const void* __restrict__ Wo, const void* __restrict__ bo,
             u16* __restrict__ xb, u16* __restrict__ wb, u16* __restrict__ bb,
             int* __restrict__ flags)
{
    const int fx  = probe_bf16(x);
    const int fwq = probe_bf16(Wq), fbq = probe_bf16(bq);
    const int fwk = probe_bf16(Wk), fbk = probe_bf16(bk);
    const int fwv = probe_bf16(Wv), fbv = probe_bf16(bv);
    const int fwo = probe_bf16(Wo), fbo = probe_bf16(bo);
    if (blockIdx.x == 0 && threadIdx.x == 0) flags[0] = fx;

    size_t idx = ((size_t)blockIdx.x * 256 + threadIdx.x) * 8;
    const size_t T_X = XS, T_W = XS + 4 * (size_t)WS, T_ALL = T_W + 4 * (size_t)BS;
    if (idx >= T_ALL) return;

    const void* src; int fl; u16* dst; size_t off;
    if (idx < T_X) {
        src = x; fl = fx; dst = xb; off = idx;
    } else if (idx < T_W) {
        size_t w = idx - T_X;
        int wi = (int)(w / WS); off = w % WS;
        src = (wi == 0) ? Wq : (wi == 1) ? Wk : (wi == 2) ? Wv : Wo;
        fl  = (wi == 0) ? fwq : (wi == 1) ? fwk : (wi == 2) ? fwv : fwo;
        dst = wb + (size_t)wi * WS;
    } else {
        size_t b = idx - T_W;
        int bi = (int)(b / BS); off = b % BS;
        src = (bi == 0) ? bq : (bi == 1) ? bk : (bi == 2) ? bv : bo;
        fl  = (bi == 0) ? fbq : (bi == 1) ? fbk : (bi == 2) ? fbv : fbo;
        dst = bb + (size_t)bi * BS;
    }
    *(uint4*)(dst + off) = cvt8(loadraw8(src, off, fl), fl);
}

// ---------------------------------------------------------------------------
// Fused QKV projection, single-barrier double-buffered LDS (unchanged from
// round 6). q,k -> [bh][n][64]; q pre-scaled. V -> TRANSPOSED [bh][d][n]
// via swapped MFMA operands for wsel==2. grid (64, 12).
// ---------------------------------------------------------------------------
__global__ __launch_bounds__(256)
void qkv_gemm(const u16* __restrict__ X, const u16* __restrict__ Wall,
              const u16* __restrict__ ball,
              u16* __restrict__ qo, u16* __restrict__ ko, u16* __restrict__ vo)
{
    __shared__ __align__(16) u16 As2[2][128 * 32];
    __shared__ __align__(16) u16 Bs2[2][128 * 32];

    const int tid  = threadIdx.x;
    const int wave = tid >> 6;
    const int lane = tid & 63;
    const int quad = lane >> 4;
    const int l16  = lane & 15;
    const int wm = wave >> 1, wn = wave & 1;

    const int m0 = blockIdx.x * 128;
    const int by = blockIdx.y;
    const int wsel = by >> 2;
    const int n0 = (by & 3) * 128;

    const u16* W  = Wall + (size_t)wsel * WS;
    const u16* bi = ball + (size_t)wsel * BS;
    const float oscale = (wsel == 0) ? 0.04419417382415922f : 1.0f;

    const u16* PA = (wsel == 2) ? W : X;
    const u16* PB = (wsel == 2) ? X : W;
    const int abase = (wsel == 2) ? n0 : m0;
    const int bbase = (wsel == 2) ? m0 : n0;

    f32x4 acc[4][4];
#pragma unroll
    for (int i = 0; i < 4; ++i)
#pragma unroll
        for (int j = 0; j < 4; ++j)
            acc[i][j] = (f32x4){0.f, 0.f, 0.f, 0.f};

    const int c1 = tid, c2 = tid + 256;
    const int r1 = c1 >> 2, k1 = (c1 & 3) * 8;
    const int r2 = c2 >> 2, k2 = (c2 & 3) * 8;

    uint4 a1 = *(const uint4*)(PA + (size_t)(abase + r1) * EMB + k1);
    uint4 a2 = *(const uint4*)(PA + (size_t)(abase + r2) * EMB + k2);
    uint4 b1 = *(const uint4*)(PB + (size_t)(bbase + r1) * EMB + k1);
    uint4 b2 = *(const uint4*)(PB + (size_t)(bbase + r2) * EMB + k2);
    *(uint4*)&As2[0][c1 * 8] = a1;
    *(uint4*)&As2[0][c2 * 8] = a2;
    *(uint4*)&Bs2[0][c1 * 8] = b1;
    *(uint4*)&Bs2[0][c2 * 8] = b2;
    a1 = *(const uint4*)(PA + (size_t)(abase + r1) * EMB + 32 + k1);
    a2 = *(const uint4*)(PA + (size_t)(abase + r2) * EMB + 32 + k2);
    b1 = *(const uint4*)(PB + (size_t)(bbase + r1) * EMB + 32 + k1);
    b2 = *(const uint4*)(PB + (size_t)(bbase + r2) * EMB + 32 + k2);
    __syncthreads();

    for (int kt = 0; kt < 16; ++kt) {
        const int cur = kt & 1;

        bf16x8 af[4], bfr[4];
#pragma unroll
        for (int i = 0; i < 4; ++i)
            af[i] = *(const bf16x8*)&As2[cur][(wm * 64 + i * 16 + l16) * 32 + quad * 8];
#pragma unroll
        for (int j = 0; j < 4; ++j)
            bfr[j] = *(const bf16x8*)&Bs2[cur][(wn * 64 + j * 16 + l16) * 32 + quad * 8];

        if (kt < 15) {
            *(uint4*)&As2[cur ^ 1][c1 * 8] = a1;
            *(uint4*)&As2[cur ^ 1][c2 * 8] = a2;
            *(uint4*)&Bs2[cur ^ 1][c1 * 8] = b1;
            *(uint4*)&Bs2[cur ^ 1][c2 * 8] = b2;
        }
        if (kt < 14) {
            const int kk0 = (kt + 2) * 32;
            a1 = *(const uint4*)(PA + (size_t)(abase + r1) * EMB + kk0 + k1);
            a2 = *(const uint4*)(PA + (size_t)(abase + r2) * EMB + kk0 + k2);
            b1 = *(const uint4*)(PB + (size_t)(bbase + r1) * EMB + kk0 + k1);
            b2 = *(const uint4*)(PB + (size_t)(bbase + r2) * EMB + kk0 + k2);
        }

#pragma unroll
        for (int i = 0; i < 4; ++i)
#pragma unroll
            for (int j = 0; j < 4; ++j)
                acc[i][j] = __builtin_amdgcn_mfma_f32_16x16x32_bf16(af[i], bfr[j], acc[i][j], 0, 0, 0);

        if (kt < 15) __syncthreads();
    }

    if (wsel != 2) {
#pragma unroll
        for (int j = 0; j < 4; ++j) {
            const int col = n0 + wn * 64 + j * 16 + l16;
            const float bv_ = bf2f(bi[col]);
            const int h = col >> 6, d = col & 63;
            u16* out = (wsel == 0) ? qo : ko;
#pragma unroll
            for (int i = 0; i < 4; ++i) {
#pragma unroll
                for (int r = 0; r < 4; ++r) {
                    const int row = m0 + wm * 64 + i * 16 + quad * 4 + r;
                    const int b = row >> 12, n = row & 4095;
                    out[(((size_t)(b * HEADS + h) * NSEQ) + n) * HD + d] =
                        f2bf((acc[i][j][r] + bv_) * oscale);
                }
            }
        }
    } else {
#pragma unroll
        for (int i = 0; i < 4; ++i) {
#pragma unroll
            for (int r = 0; r < 4; ++r) {
                const int dglob = n0 + wm * 64 + i * 16 + quad * 4 + r;
                const float bv_ = bf2f(bi[dglob]);
                const int h = dglob >> 6, dd = dglob & 63;
#pragma unroll
                for (int j = 0; j < 4; ++j) {
                    const int ncol = m0 + wn * 64 + j * 16 + l16;
                    const int b = ncol >> 12, n = ncol & 4095;
                    vo[((size_t)(b * HEADS + h) * HD + dd) * NSEQ + n] =
                        f2bf(acc[i][j][r] + bv_);
                }
            }
        }
    }
}

// ---------------------------------------------------------------------------
// MFMA flash attention v6 -- BARRIER-FREE. q,k: [bh][n][64]; vt: [bh][d][n].
//  - NO K/V LDS staging: all 4 waves read identical fragment addresses, and
//    the per-XCD K/V working set (~2 MB) is L2-resident, so B-operand
//    fragments for QK^T (K[j][d0:d0+8]) and PV (V^T[d][n0:n0+8]) are loaded
//    directly from global as per-lane 16B loads. LDS staging of L2-fitting
//    data was pure overhead.
//  - ones-row denominator fragment is a register constant (l16==0 ? 1 : 0).
//  - only LDS: per-wave Pb transpose (9 KB) -> ZERO __syncthreads; waves run
//    independently, latency hidden by TLP.
//  - fixed-max softmax (m=0), fminf(S,40) guard; band skips; XCD swizzle.
// grid (64, 16).
// ---------------------------------------------------------------------------
#define KP 72
__global__ __launch_bounds__(256)
void attn_mfma(const u16* __restrict__ q, const u16* __restrict__ k,
               const u16* __restrict__ vt, u16* __restrict__ ao)
{
    __shared__ __align__(16) u16 Pb[4][16 * KP];

    const int tid  = threadIdx.x;
    const int wave = tid >> 6;
    const int lane = tid & 63;
    const int quad = lane >> 4;
    const int l16  = lane & 15;

    int wg = blockIdx.y * 64 + blockIdx.x;
    wg = (wg & 7) * 128 + (wg >> 3);       // bijective XCD swizzle (1024 = 8*128)
    const int bh = wg >> 6;
    const int q0 = (wg & 63) * 64;

    const int qw = q0 + wave * 16;
    const size_t base = (size_t)bh * NSEQ * HD;
    const bool interior = (q0 >= 128) && (q0 <= NSEQ - 192);

    bf16x8 qa0 = *(const bf16x8*)(q + base + (size_t)(qw + l16) * HD + quad * 8);
    bf16x8 qa1 = *(const bf16x8*)(q + base + (size_t)(qw + l16) * HD + 32 + quad * 8);

    // ones-row denominator B-fragment: row (64+l16) of [ones; zeros] pattern
    const u16 onesv = (l16 == 0) ? (u16)0x3f80 : (u16)0;
    bf16x8 vb4;
#pragma unroll
    for (int e = 0; e < 8; ++e) vb4[e] = (short)onesv;

    f32x4 O[4], O4;
#pragma unroll
    for (int t = 0; t < 4; ++t) O[t] = (f32x4){0.f, 0.f, 0.f, 0.f};
    O4 = (f32x4){0.f, 0.f, 0.f, 0.f};

    // Pb column swizzle: phys col16-block = logical block ^ (row>>2 within 16)
    const int pacol = (quad * 8) ^ ((l16 >> 2) << 4);

    for (int c = 0; c < 5; ++c) {
        const int kbase = q0 - 128 + c * 64;
        const int gdk = kbase - qw;       // wave-uniform
        const bool act = (gdk <= 143) && (gdk >= -191) &&
                         (kbase > -64) && (kbase < NSEQ);
        if (!act) continue;

        // ---- QK^T: K fragments straight from global (L1/L2-resident) ----
        f32x4 sv[4];
#pragma unroll
        for (int t = 0; t < 4; ++t) {
            const int dk = gdk + t * 16;
            if (dk >= -143 && dk <= 143) {
                int kg = kbase + t * 16 + l16;
                kg = (kg < 0) ? 0 : (kg > NSEQ - 1 ? NSEQ - 1 : kg);
                const u16* kp = k + base + (size_t)kg * HD + quad * 8;
                bf16x8 b0 = *(const bf16x8*)(kp);
                bf16x8 b1 = *(const bf16x8*)(kp + 32);
                f32x4 sacc = (f32x4){0.f, 0.f, 0.f, 0.f};
                sacc = __builtin_amdgcn_mfma_f32_16x16x32_bf16(qa0, b0, sacc, 0, 0, 0);
                sacc = __builtin_amdgcn_mfma_f32_16x16x32_bf16(qa1, b1, sacc, 0, 0, 0);
                if (!interior || dk < -113 || dk > 113) {
                    const int jg = kbase + t * 16 + l16;
                    const bool jok = ((unsigned)jg) < (unsigned)NSEQ;
#pragma unroll
                    for (int r = 0; r < 4; ++r) {
                        const int iq = qw + quad * 4 + r;
                        const bool band = ((unsigned)(iq - jg + WINDOW)) <= (unsigned)(2 * WINDOW);
                        if (!(jok && band)) sacc[r] = -1e30f;
                    }
                }
                sv[t] = sacc;
            } else {
                sv[t] = (f32x4){-1e30f, -1e30f, -1e30f, -1e30f};
            }
        }

        // ---- fixed-max softmax numerator: P = exp(min(S,40)); masked -> 0
#pragma unroll
        for (int t = 0; t < 4; ++t) {
            const int tc = (t ^ quad) * 16 + l16;   // swizzled phys column
#pragma unroll
            for (int r = 0; r < 4; ++r) {
                const float pv = __expf(fminf(sv[t][r], 40.f));
                Pb[wave][(quad * 4 + r) * KP + tc] = f2bf(pv);
            }
        }

        // ---- PV: V^T fragments straight from global ----
#pragma unroll
        for (int ks2 = 0; ks2 < 2; ++ks2) {
            bf16x8 pa = *(const bf16x8*)&Pb[wave][l16 * KP + (pacol ^ (ks2 * 32))];
            int kc = kbase + ks2 * 32 + quad * 8;
            kc = (kc < 0) ? 0 : (kc > NSEQ - 8 ? NSEQ - 8 : kc);
#pragma unroll
            for (int t = 0; t < 4; ++t) {
                const int vr = t * 16 + l16;        // d-row of V^T
                bf16x8 vb = *(const bf16x8*)(vt + base + (size_t)vr * NSEQ + kc);
                O[t] = __builtin_amdgcn_mfma_f32_16x16x32_bf16(pa, vb, O[t], 0, 0, 0);
            }
            O4 = __builtin_amdgcn_mfma_f32_16x16x32_bf16(pa, vb4, O4, 0, 0, 0);
        }
    }

    const int bb = bh >> 3, hh = bh & 7;
    float rl[4];
#pragma unroll
    for (int r = 0; r < 4; ++r) {
        const float ls = __shfl(O4[r], lane & 48, 64);   // col 0 lives in lane quad*16
        rl[r] = 1.f / ls;
    }
#pragma unroll
    for (int t = 0; t < 4; ++t)
#pragma unroll
        for (int r = 0; r < 4; ++r) {
            const int iq = qw + quad * 4 + r;
            ao[((size_t)(bb * NSEQ + iq)) * EMB + hh * HD + t * 16 + l16] =
                f2bf(O[t][r] * rl[r]);
        }
}

// ---------------------------------------------------------------------------
// Output projection, single-barrier double-buffered (unchanged from round 6).
// grid (64, 4).
// ---------------------------------------------------------------------------
__global__ __launch_bounds__(256)
void out_gemm(const u16* __restrict__ A, const u16* __restrict__ W,
              const u16* __restrict__ bias, void* __restrict__ out,
              const int* __restrict__ flags)
{
    __shared__ __align__(16) u16 As2[2][128 * 32];
    __shared__ __align__(16) u16 Bs2[2][128 * 32];

    const int tid  = threadIdx.x;
    const int wave = tid >> 6;
    const int lane = tid & 63;
    const int quad = lane >> 4;
    const int l16  = lane & 15;
    const int wm = wave >> 1, wn = wave & 1;

    const int m0 = blockIdx.x * 128;
    const int n0 = blockIdx.y * 128;
    const int fo = flags[0];

    f32x4 acc[4][4];
#pragma unroll
    for (int i = 0; i < 4; ++i)
#pragma unroll
        for (int j = 0; j < 4; ++j)
            acc[i][j] = (f32x4){0.f, 0.f, 0.f, 0.f};

    const int c1 = tid, c2 = tid + 256;
    const int r1 = c1 >> 2, k1 = (c1 & 3) * 8;
    const int r2 = c2 >> 2, k2 = (c2 & 3) * 8;

    uint4 a1 = *(const uint4*)(A + (size_t)(m0 + r1) * EMB + k1);
    uint4 a2 = *(const uint4*)(A + (size_t)(m0 + r2) * EMB + k2);
    uint4 b1 = *(const uint4*)(W + (size_t)(n0 + r1) * EMB + k1);
    uint4 b2 = *(const uint4*)(W + (size_t)(n0 + r2) * EMB + k2);
    *(uint4*)&As2[0][c1 * 8] = a1;
    *(uint4*)&As2[0][c2 * 8] = a2;
    *(uint4*)&Bs2[0][c1 * 8] = b1;
    *(uint4*)&Bs2[0][c2 * 8] = b2;
    a1 = *(const uint4*)(A + (size_t)(m0 + r1) * EMB + 32 + k1);
    a2 = *(const uint4*)(A + (size_t)(m0 + r2) * EMB + 32 + k2);
    b1 = *(const uint4*)(W + (size_t)(n0 + r1) * EMB + 32 + k1);
    b2 = *(const uint4*)(W + (size_t)(n0 + r2) * EMB + 32 + k2);
    __syncthreads();

    for (int kt = 0; kt < 16; ++kt) {
        const int cur = kt & 1;

        bf16x8 af[4], bfr[4];
#pragma unroll
        for (int i = 0; i < 4; ++i)
            af[i] = *(const bf16x8*)&As2[cur][(wm * 64 + i * 16 + l16) * 32 + quad * 8];
#pragma unroll
        for (int j = 0; j < 4; ++j)
            bfr[j] = *(const bf16x8*)&Bs2[cur][(wn * 64 + j * 16 + l16) * 32 + quad * 8];

        if (kt < 15) {
            *(uint4*)&As2[cur ^ 1][c1 * 8] = a1;
            *(uint4*)&As2[cur ^ 1][c2 * 8] = a2;
            *(uint4*)&Bs2[cur ^ 1][c1 * 8] = b1;
            *(uint4*)&Bs2[cur ^ 1][c2 * 8] = b2;
        }
        if (kt < 14) {
            const int kk0 = (kt + 2) * 32;
            a1 = *(const uint4*)(A + (size_t)(m0 + r1) * EMB + kk0 + k1);
            a2 = *(const uint4*)(A + (size_t)(m0 + r2) * EMB + kk0 + k2);
            b1 = *(const uint4*)(W + (size_t)(n0 + r1) * EMB + kk0 + k1);
            b2 = *(const uint4*)(W + (size_t)(n0 + r2) * EMB + kk0 + k2);
        }

#pragma unroll
        for (int i = 0; i < 4; ++i)
#pragma unroll
            for (int j = 0; j < 4; ++j)
                acc[i][j] = __builtin_amdgcn_mfma_f32_16x16x32_bf16(af[i], bfr[j], acc[i][j], 0, 0, 0);

        if (kt < 15) __syncthreads();
    }

#pragma unroll
    for (int j = 0; j < 4; ++j) {
        const int col = n0 + wn * 64 + j * 16 + l16;
        const float bv_ = bf2f(bias[col]);
#pragma unroll
        for (int i = 0; i < 4; ++i) {
#pragma unroll
            for (int r = 0; r < 4; ++r) {
                const int row = m0 + wm * 64 + i * 16 + quad * 4 + r;
                const float val = acc[i][j][r] + bv_;
                const size_t idx = (size_t)row * EMB + col;
                if (fo) ((u16*)out)[idx] = f2bf(val);
                else    ((float*)out)[idx] = val;
            }
        }
    }
}

extern "C" void kernel_launch(void* const* d_in, const int* in_sizes, int n_in,
                              void* d_out, int out_size, void* d_ws, size_t ws_size,
                              hipStream_t stream)
{
    const size_t HSZ  = (size_t)BATCH * HEADS * NSEQ * HD;   // 4.19M elems
    char* base = (char*)d_ws;
    int* flags = (int*)base;
    const size_t off = 256;

    u16* xb = (u16*)(base + off);            // 4.19M elems
    u16* wb = xb + XS;                       // 4 * 262144
    u16* bb = wb + 4 * (size_t)WS;           // 4 * 512
    u16* kk = bb + 4 * (size_t)BS;           // k
    u16* vv = kk + HSZ;                      // v (TRANSPOSED [bh][d][n])
    u16* ao = vv + HSZ;                      // ao
    u16* qq = ao + HSZ;                      // q (tier-1)

    const size_t need_t1 = off + 2 * (XS + 4 * (size_t)WS + 4 * (size_t)BS + 4 * HSZ);
    if (ws_size < need_t1) {
        qq = (u16*)d_out;                    // q dead before out_gemm writes d_out
    }

    prepass<<<dim3(2561), 256, 0, stream>>>(d_in[0], d_in[1], d_in[2], d_in[3],
                                            d_in[4], d_in[5], d_in[6], d_in[7],
                                            d_in[8], xb, wb, bb, flags);
    qkv_gemm<<<dim3(64, 12), 256, 0, stream>>>(xb, wb, bb, qq, kk, vv);
    attn_mfma<<<dim3(64, 16), 256, 0, stream>>>(qq, kk, vv, ao);
    out_gemm<<<dim3(64, 4), 256, 0, stream>>>(ao, wb + 3 * (size_t)WS, bb + 3 * (size_t)BS,
                                              d_out, flags);
}